// Round 1
// baseline (306.088 us; speedup 1.0000x reference)
//
#include <hip/hip_runtime.h>
#include <hip/hip_cooperative_groups.h>

namespace cg = cooperative_groups;

// Problem constants
//   m1:(1,1,4096,64) m2:(1,1,6144,64) m3:(1,1,8192,64) m4:(1,1,4096,64) fp32
//   WQ_w:(3,64,64) WQ_b:(3,64) WK_w:(4,3,64,64) WK_b:(4,3,64)
//   out:(1,4096,32) fp32
//
// Workspace layout (float units):
//   Qb   bf16 [4096][64]                 @ 0          (131072 fl)
//   Kb   bf16 per module [T_m][64]       @ 131072     (720896 fl)
//   SP   fp32 356 slots x 2048 (d*32+e)  @ 851968     (729088 fl)
//   TD   fp32 dense t2 per module        @ 1581056    (22528 fl)
//   CTAB int[4][64][2] tile c-bounds     @ 1603584    (512)

#define QB_OFF   0
#define KB_OFF   131072
#define SP_OFF   851968
#define TD_OFF   1581056
#define C_OFF    1603584

typedef __attribute__((ext_vector_type(8))) short short8;    // bf16 frag (4 VGPR)
typedef __attribute__((ext_vector_type(4))) float floatx4;   // MFMA C/D

__device__ __forceinline__ unsigned short f2bf(float f) {
    union { float f; unsigned u; } v; v.f = f;
    unsigned r = v.u + 0x7fff + ((v.u >> 16) & 1);   // RNE
    return (unsigned short)(r >> 16);
}

#define MFMA16(a,b,c) __builtin_amdgcn_mfma_f32_16x16x32_bf16((a),(b),(c),0,0,0)

// ===========================================================================
// MERGED cooperative kernel: 416 blocks x 256.
//   Phase A (all 416 blocks): MLPs + bf16 Q/K stores + chunk K^T.V sums +
//            dense timestamps + zero out.           (== old k_fused + zeroing)
//   grid.sync()
//   Phase B (blocks 0..129): 4-way-parallel hierarchical prefix scan of SP
//            (128 blocks, 64 entries x 4 slot-quarters each; serial depth
//            129 -> ~33x2) + ctab binary searches.  (== old k_prefix, 4x TLP)
//   grid.sync()
//   Phase C (512 logical query blocks on 416 real; doubled blocks get only
//            slot-1 (light/empty) work).            (== old k_query)
// LDS 61.2 KB -> 2 blocks/CU; 416 <= 512 co-resident capacity.
__global__ __launch_bounds__(256, 2) void k_all(
    const float* __restrict__ x0, const float* __restrict__ x1,
    const float* __restrict__ x2, const float* __restrict__ x3,
    const float* __restrict__ wq_w, const float* __restrict__ wq_b,
    const float* __restrict__ wk_w, const float* __restrict__ wk_b,
    float* __restrict__ ws, float* __restrict__ out)
{
    __shared__ unsigned short SH[6*4608 + 2304];  // 59904 B, phase-overlaid
    __shared__ float SF[320];                     // scan partials / tq+tcs

    const int tid = threadIdx.x;
    const int bid = blockIdx.x;

    const float* Xs[4] = {x0, x1, x2, x3};
    const int rowoff[4] = {0, 4096, 10240, 18432};
    const int spoff[4]  = {0, 65, 162, 291};
    const int nslots[4] = {65, 97, 129, 65};
    const int Tm[4]     = {4096, 6144, 8192, 4096};

    const int w    = tid >> 6;      // wave id
    const int lane = tid & 63;
    const int lm   = lane & 15;
    const int q    = lane >> 4;
    const int col  = w*16 + lm;

    // ================= Phase A: fused MLP + chunk sums =================
    {
        unsigned short* H0 = SH;              // act ping [row][col]
        unsigned short* H1 = SH + 4608;       // act pong
        unsigned short* Wt = SH + 2*4608;     // W^T all layers [l][c][d]
        unsigned short* KT = SH + 5*4608;     // K^T [d][j]
        unsigned short* VT = SH + 6*4608;     // V^T [e][j]

        int task, rb;
        if (bid < 64)       { task = 0; rb = bid; }
        else if (bid < 128) { task = 1; rb = bid - 64; }
        else if (bid < 224) { task = 2; rb = bid - 128; }
        else if (bid < 352) { task = 3; rb = bid - 224; }
        else                { task = 4; rb = bid - 352; }

        const float* X; const float* W; const float* Bv; int mm = -1;
        if (task == 0) { X = x0; W = wq_w; Bv = wq_b; }
        else {
            mm = task - 1;
            X = Xs[mm]; W = wk_w + mm*3*64*64; Bv = wk_b + mm*3*64;
        }

        const int row0 = rb * 64;

        // one up-front global batch: X tile + all 3 W layers
        {
            const float4* X4 = (const float4*)(X + (size_t)row0*64);
            #pragma unroll
            for (int k = 0; k < 4; ++k) {
                int idx = k*256 + tid;
                float4 v = X4[idx];
                int rr = idx >> 4, c4 = (idx & 15) * 4;
                ushort4 h;
                h.x = f2bf(v.x); h.y = f2bf(v.y); h.z = f2bf(v.z); h.w = f2bf(v.w);
                *(ushort4*)&H0[rr*72 + c4] = h;
            }
            const float4* W4 = (const float4*)W;
            #pragma unroll
            for (int k = 0; k < 12; ++k) {
                int idx = k*256 + tid;
                float4 v = W4[idx];
                int l = idx >> 10, rest = idx & 1023;
                int d = rest >> 4, c4 = (rest & 15) * 4;
                Wt[l*4608 + (c4+0)*72 + d] = f2bf(v.x);
                Wt[l*4608 + (c4+1)*72 + d] = f2bf(v.y);
                Wt[l*4608 + (c4+2)*72 + d] = f2bf(v.z);
                Wt[l*4608 + (c4+3)*72 + d] = f2bf(v.w);
            }
        }
        // task-0 blocks zero the output (replaces old k_prefix bids 34..41)
        if (task == 0) {
            float4 z = make_float4(0.f, 0.f, 0.f, 0.f);
            ((float4*)out)[bid*512 + tid] = z;
            ((float4*)out)[bid*512 + 256 + tid] = z;
        }
        // dense timestamps (fp32, never through bf16)
        if (task > 0 && tid < 64)
            ws[TD_OFF + rowoff[mm] + row0 + tid] = X[(size_t)(row0 + tid)*64 + 63];
        __syncthreads();

        // 3 MFMA layers, ONE barrier each (ping-pong)
        #pragma unroll 1
        for (int l = 0; l < 3; ++l) {
            const unsigned short* Hin  = (l & 1) ? H1 : H0;
            unsigned short*       Hout = (l & 1) ? H0 : H1;
            float bias = Bv[l*64 + col];
            short8 b0 = *(const short8*)&Wt[l*4608 + col*72 + q*8];
            short8 b1 = *(const short8*)&Wt[l*4608 + col*72 + 32 + q*8];
            #pragma unroll
            for (int mt = 0; mt < 4; ++mt) {
                floatx4 acc = {bias, bias, bias, bias};
                short8 a0 = *(const short8*)&Hin[(mt*16+lm)*72 + q*8];
                short8 a1 = *(const short8*)&Hin[(mt*16+lm)*72 + 32 + q*8];
                acc = MFMA16(a0, b0, acc);
                acc = MFMA16(a1, b1, acc);
                int r0 = mt*16 + q*4;
                #pragma unroll
                for (int r = 0; r < 4; ++r) {
                    float f = acc[r];
                    if (l < 2) f = fmaxf(f, 0.0f);
                    unsigned short hb = f2bf(f);
                    Hout[(r0+r)*72 + col] = hb;
                    if (l == 2 && task > 0) KT[col*72 + r0 + r] = hb;
                }
            }
            __syncthreads();
        }

        // coalesced bf16 global store of final activations (in H1)
        {
            unsigned short* dst = (task == 0)
                ? (unsigned short*)(ws + QB_OFF)
                : (unsigned short*)(ws + KB_OFF) + (size_t)rowoff[mm]*64;
            #pragma unroll
            for (int k = 0; k < 4; ++k) {
                int idx = k*256 + tid;
                int rr = idx >> 4, c4 = (idx & 15) * 4;
                *(ushort4*)&dst[(size_t)(row0 + rr)*64 + c4] = *(ushort4*)&H1[rr*72 + c4];
            }
        }

        if (task > 0) {
            // stage V^T (X cols 0..31) + zero module slot 0
            #pragma unroll
            for (int k = 0; k < 2; ++k) {
                int idx = k*256 + tid;
                int j = idx >> 3, e4 = (idx & 7) * 4;
                float4 v = *(const float4*)&X[(size_t)(row0 + j)*64 + e4];
                VT[(e4+0)*72 + j] = f2bf(v.x);
                VT[(e4+1)*72 + j] = f2bf(v.y);
                VT[(e4+2)*72 + j] = f2bf(v.z);
                VT[(e4+3)*72 + j] = f2bf(v.w);
            }
            float* spbase = ws + SP_OFF + (size_t)spoff[mm]*2048;
            if (rb == 0)
                for (int idx = tid; idx < 2048; idx += 256) spbase[idx] = 0.0f;
            __syncthreads();

            // chunk sum S[d][e] = sum_j K[j][d] V[j][e]; wave w owns d-tile w
            float* slot = spbase + (size_t)(rb + 1) * 2048;
            #pragma unroll
            for (int nt = 0; nt < 2; ++nt) {
                floatx4 acc = {0.f, 0.f, 0.f, 0.f};
                #pragma unroll
                for (int ks = 0; ks < 2; ++ks) {
                    short8 aa = *(const short8*)&KT[col*72 + ks*32 + q*8];
                    short8 bb = *(const short8*)&VT[(nt*16+lm)*72 + ks*32 + q*8];
                    acc = MFMA16(aa, bb, acc);
                }
                #pragma unroll
                for (int r = 0; r < 4; ++r)
                    slot[(w*16 + q*4 + r)*32 + nt*16 + lm] = acc[r];
            }
        }
    }

    __threadfence();
    cg::this_grid().sync();

    // ================= Phase B: 4-way-parallel scan + ctab =================
    if (bid < 128) {
        // block = (module m, 64-entry group); thread = (entry e, slot-quarter)
        const int m   = bid >> 5;
        const int e   = tid & 63;
        const int qtr = tid >> 6;               // wave id = quarter
        const int entry = (bid & 31)*64 + e;
        const int n = nslots[m];
        float* p = ws + SP_OFF + (size_t)spoff[m]*2048 + entry;
        const int k0 = (qtr*n) >> 2;
        const int k1 = ((qtr+1)*n) >> 2;
        float s = 0.0f;
        #pragma unroll 8
        for (int k = k0; k < k1; ++k) s += p[(size_t)k*2048];
        SF[qtr*64 + e] = s;
        __syncthreads();
        float base = 0.0f;
        #pragma unroll
        for (int q2 = 0; q2 < 3; ++q2) if (q2 < qtr) base += SF[q2*64 + e];
        s = base;
        #pragma unroll 8
        for (int k = k0; k < k1; ++k) {
            s += p[(size_t)k*2048];             // L2-hot reload
            p[(size_t)k*2048] = s;
        }
    } else if (bid < 130) {
        const float* td = ws + TD_OFF;
        int* ctab = (int*)(ws + C_OFF);
        int g = (bid - 128)*256 + tid;          // 0..511
        int m = g >> 7, tile = (g >> 1) & 63, bound = g & 1;
        float t = td[tile*64 + (bound ? 63 : 0)];
        const float* t2 = td + rowoff[m];
        int lo = 0, hi = Tm[m];
        while (lo < hi) {
            int mid = (lo + hi) >> 1;
            if (t2[mid] <= t) lo = mid + 1; else hi = mid;
        }
        ctab[g] = lo;
    }

    __threadfence();
    cg::this_grid().sync();

    // ================= Phase C: tiled MFMA query =================
    {
        unsigned short* qs = SH;                 // Q  [i][d]
        unsigned short* kc = SH + 4608;          // K  [j][d]  (chunk)
        unsigned short* ps = SH + 2*4608;        // masked P [i][j]
        unsigned short* vt = SH + 3*4608;        // V^T [e][j]
        unsigned short* st = SH + 3*4608 + 2304; // S^T [e][d] (slot 0 only)
        float* tq  = SF;                         // t1 tile (fp32!)
        float* tcs = SF + 64;                    // t2 chunk (fp32!)

        // 512 logical blocks on 416 real; doubled blocks (bid<96) take
        // lb+416, which is always slot==1 (light / frequently empty).
        for (int lb = bid; lb < 512; lb += 416) {
            __syncthreads();                     // protect LDS reuse
            const int m    = lb & 3;
            const int tile = (lb >> 2) & 63;
            const int slot = lb >> 8;            // 0 or 1
            const int i0   = tile * 64;
            const float* X = Xs[m];

            const int* ctab = (const int*)(ws + C_OFF);
            const int c_lo = ctab[m*128 + tile*2 + 0];
            const int c_hi = ctab[m*128 + tile*2 + 1];
            const int B0   = c_lo >> 6;
            const int Bhi  = (c_hi + 63) >> 6;

            if (slot == 1 && B0 + 1 >= Bhi) continue;

            const unsigned short* Qg = (const unsigned short*)(ws + QB_OFF);
            const unsigned short* Kg = (const unsigned short*)(ws + KB_OFF) + (size_t)rowoff[m]*64;
            const float* td = ws + TD_OFF;
            const float* sp = ws + SP_OFF + (size_t)(spoff[m] + B0)*2048;

            #pragma unroll
            for (int k = 0; k < 4; ++k) {
                int idx = k*256 + tid;
                int rr = idx >> 4, c4 = (idx & 15) * 4;
                *(ushort4*)&qs[rr*72 + c4] = *(const ushort4*)&Qg[(size_t)(i0 + rr)*64 + c4];
            }
            if (slot == 0) {
                #pragma unroll
                for (int k = 0; k < 8; ++k) {
                    int idx = k*256 + tid;
                    int d = idx >> 5, ee = idx & 31;
                    st[ee*72 + d] = f2bf(sp[idx]);
                }
            }
            if (tid < 64) tq[tid] = td[i0 + tid];
            __syncthreads();

            float t1v[16];
            #pragma unroll
            for (int mt = 0; mt < 4; ++mt)
                #pragma unroll
                for (int r = 0; r < 4; ++r)
                    t1v[mt*4 + r] = tq[mt*16 + q*4 + r];

            short8 qa[4][2];
            #pragma unroll
            for (int mt = 0; mt < 4; ++mt) {
                qa[mt][0] = *(const short8*)&qs[(mt*16+lm)*72 + q*8];
                qa[mt][1] = *(const short8*)&qs[(mt*16+lm)*72 + 32 + q*8];
            }

            floatx4 accO[2];
            accO[0] = (floatx4){0.f, 0.f, 0.f, 0.f};
            accO[1] = (floatx4){0.f, 0.f, 0.f, 0.f};

            if (slot == 0) {
                #pragma unroll
                for (int nt = 0; nt < 2; ++nt) {
                    #pragma unroll
                    for (int ks = 0; ks < 2; ++ks) {
                        short8 b = *(const short8*)&st[(nt*16+lm)*72 + ks*32 + q*8];
                        accO[nt] = MFMA16(qa[w][ks], b, accO[nt]);
                    }
                }
            }

            #pragma unroll 1
            for (int B = B0 + slot; B < Bhi; B += 2) {
                __syncthreads();
                #pragma unroll
                for (int k = 0; k < 4; ++k) {
                    int idx = k*256 + tid;
                    int j = idx >> 4, c4 = (idx & 15) * 4;
                    *(ushort4*)&kc[j*72 + c4] = *(const ushort4*)&Kg[(size_t)(B*64 + j)*64 + c4];
                }
                #pragma unroll
                for (int k = 0; k < 2; ++k) {
                    int idx = k*256 + tid;
                    int j = idx >> 3, e4 = (idx & 7) * 4;
                    float4 v = *(const float4*)&X[(size_t)(B*64 + j)*64 + e4];
                    vt[(e4+0)*72 + j] = f2bf(v.x);
                    vt[(e4+1)*72 + j] = f2bf(v.y);
                    vt[(e4+2)*72 + j] = f2bf(v.z);
                    vt[(e4+3)*72 + j] = f2bf(v.w);
                }
                if (tid < 64) tcs[tid] = td[rowoff[m] + B*64 + tid];
                __syncthreads();

                {
                    short8 bk0 = *(const short8*)&kc[(w*16+lm)*72 + q*8];
                    short8 bk1 = *(const short8*)&kc[(w*16+lm)*72 + 32 + q*8];
                    float t2j = tcs[w*16 + lm];
                    #pragma unroll
                    for (int mt = 0; mt < 4; ++mt) {
                        floatx4 f = {0.f, 0.f, 0.f, 0.f};
                        f = MFMA16(qa[mt][0], bk0, f);
                        f = MFMA16(qa[mt][1], bk1, f);
                        #pragma unroll
                        for (int r = 0; r < 4; ++r) {
                            float pv = (t2j <= t1v[mt*4 + r]) ? f[r] : 0.0f;
                            ps[(mt*16 + q*4 + r)*72 + w*16 + lm] = f2bf(pv);
                        }
                    }
                }
                __syncthreads();

                {
                    short8 pa0 = *(const short8*)&ps[(w*16+lm)*72 + q*8];
                    short8 pa1 = *(const short8*)&ps[(w*16+lm)*72 + 32 + q*8];
                    #pragma unroll
                    for (int nt = 0; nt < 2; ++nt) {
                        short8 bv0 = *(const short8*)&vt[(nt*16+lm)*72 + q*8];
                        short8 bv1 = *(const short8*)&vt[(nt*16+lm)*72 + 32 + q*8];
                        accO[nt] = MFMA16(pa0, bv0, accO[nt]);
                        accO[nt] = MFMA16(pa1, bv1, accO[nt]);
                    }
                }
            }

            #pragma unroll
            for (int nt = 0; nt < 2; ++nt)
                #pragma unroll
                for (int r = 0; r < 4; ++r) {
                    int i = w*16 + q*4 + r;
                    int e = nt*16 + lm;
                    atomicAdd(&out[(size_t)(i0 + i)*32 + e], accO[nt][r]);
                }
        }
    }
}

// ===========================================================================
// LEGACY fallback path (verified baseline, used only if cooperative launch
// is rejected by the runtime/graph-capture).
// ===========================================================================
__global__ __launch_bounds__(256) void k_fused(
    const float* __restrict__ x0, const float* __restrict__ x1,
    const float* __restrict__ x2, const float* __restrict__ x3,
    const float* __restrict__ wq_w, const float* __restrict__ wq_b,
    const float* __restrict__ wk_w, const float* __restrict__ wk_b,
    float* __restrict__ ws)
{
    __shared__ unsigned short H0[64*72];
    __shared__ unsigned short H1[64*72];
    __shared__ unsigned short Wt[3][64*72];
    __shared__ unsigned short KT[64*72];
    __shared__ unsigned short VT[32*72];

    const int tid = threadIdx.x;
    const int bid = blockIdx.x;

    int task, rb;
    if (bid < 64)       { task = 0; rb = bid; }
    else if (bid < 128) { task = 1; rb = bid - 64; }
    else if (bid < 224) { task = 2; rb = bid - 128; }
    else if (bid < 352) { task = 3; rb = bid - 224; }
    else                { task = 4; rb = bid - 352; }

    const float* Xs[4] = {x0, x1, x2, x3};
    const int rowoff[4] = {0, 4096, 10240, 18432};
    const int spoff[4]  = {0, 65, 162, 291};

    const float* X; const float* W; const float* Bv; int mm = -1;
    if (task == 0) { X = x0; W = wq_w; Bv = wq_b; }
    else {
        mm = task - 1;
        X = Xs[mm]; W = wk_w + mm*3*64*64; Bv = wk_b + mm*3*64;
    }

    const int row0 = rb * 64;

    {
        const float4* X4 = (const float4*)(X + (size_t)row0*64);
        #pragma unroll
        for (int k = 0; k < 4; ++k) {
            int idx = k*256 + tid;
            float4 v = X4[idx];
            int rr = idx >> 4, c4 = (idx & 15) * 4;
            ushort4 h;
            h.x = f2bf(v.x); h.y = f2bf(v.y); h.z = f2bf(v.z); h.w = f2bf(v.w);
            *(ushort4*)&H0[rr*72 + c4] = h;
        }
        const float4* W4 = (const float4*)W;
        #pragma unroll
        for (int k = 0; k < 12; ++k) {
            int idx = k*256 + tid;
            float4 v = W4[idx];
            int l = idx >> 10, rest = idx & 1023;
            int d = rest >> 4, c4 = (rest & 15) * 4;
            Wt[l][(c4+0)*72 + d] = f2bf(v.x);
            Wt[l][(c4+1)*72 + d] = f2bf(v.y);
            Wt[l][(c4+2)*72 + d] = f2bf(v.z);
            Wt[l][(c4+3)*72 + d] = f2bf(v.w);
        }
    }
    if (task > 0 && tid < 64)
        ws[TD_OFF + rowoff[mm] + row0 + tid] = X[(size_t)(row0 + tid)*64 + 63];
    __syncthreads();

    const int w    = tid >> 6;
    const int lane = tid & 63;
    const int lm   = lane & 15;
    const int q    = lane >> 4;
    const int col  = w*16 + lm;

    #pragma unroll 1
    for (int l = 0; l < 3; ++l) {
        const unsigned short* Hin  = (l & 1) ? H1 : H0;
        unsigned short*       Hout = (l & 1) ? H0 : H1;
        float bias = Bv[l*64 + col];
        short8 b0 = *(const short8*)&Wt[l][col*72 + q*8];
        short8 b1 = *(const short8*)&Wt[l][col*72 + 32 + q*8];
        #pragma unroll
        for (int mt = 0; mt < 4; ++mt) {
            floatx4 acc = {bias, bias, bias, bias};
            short8 a0 = *(const short8*)&Hin[(mt*16+lm)*72 + q*8];
            short8 a1 = *(const short8*)&Hin[(mt*16+lm)*72 + 32 + q*8];
            acc = MFMA16(a0, b0, acc);
            acc = MFMA16(a1, b1, acc);
            int r0 = mt*16 + q*4;
            #pragma unroll
            for (int r = 0; r < 4; ++r) {
                float f = acc[r];
                if (l < 2) f = fmaxf(f, 0.0f);
                unsigned short hb = f2bf(f);
                Hout[(r0+r)*72 + col] = hb;
                if (l == 2 && task > 0) KT[col*72 + r0 + r] = hb;
            }
        }
        __syncthreads();
    }

    {
        unsigned short* dst = (task == 0)
            ? (unsigned short*)(ws + QB_OFF)
            : (unsigned short*)(ws + KB_OFF) + (size_t)rowoff[mm]*64;
        #pragma unroll
        for (int k = 0; k < 4; ++k) {
            int idx = k*256 + tid;
            int rr = idx >> 4, c4 = (idx & 15) * 4;
            *(ushort4*)&dst[(size_t)(row0 + rr)*64 + c4] = *(ushort4*)&H1[rr*72 + c4];
        }
    }
    if (task == 0) return;

    {
        #pragma unroll
        for (int k = 0; k < 2; ++k) {
            int idx = k*256 + tid;
            int j = idx >> 3, e4 = (idx & 7) * 4;
            float4 v = *(const float4*)&X[(size_t)(row0 + j)*64 + e4];
            VT[(e4+0)*72 + j] = f2bf(v.x);
            VT[(e4+1)*72 + j] = f2bf(v.y);
            VT[(e4+2)*72 + j] = f2bf(v.z);
            VT[(e4+3)*72 + j] = f2bf(v.w);
        }
    }
    float* spbase = ws + SP_OFF + (size_t)spoff[mm]*2048;
    if (rb == 0)
        for (int idx = tid; idx < 2048; idx += 256) spbase[idx] = 0.0f;
    __syncthreads();

    {
        float* slot = spbase + (size_t)(rb + 1) * 2048;
        #pragma unroll
        for (int nt = 0; nt < 2; ++nt) {
            floatx4 acc = {0.f, 0.f, 0.f, 0.f};
            #pragma unroll
            for (int ks = 0; ks < 2; ++ks) {
                short8 aa = *(const short8*)&KT[col*72 + ks*32 + q*8];
                short8 bb = *(const short8*)&VT[(nt*16+lm)*72 + ks*32 + q*8];
                acc = MFMA16(aa, bb, acc);
            }
            #pragma unroll
            for (int r = 0; r < 4; ++r)
                slot[(w*16 + q*4 + r)*32 + nt*16 + lm] = acc[r];
        }
    }
}

__global__ __launch_bounds__(256) void k_prefix(float* __restrict__ ws,
                                                float* __restrict__ out)
{
    const int nslots[4] = {65, 97, 129, 65};
    const int spoff[4]  = {0, 65, 162, 291};
    const int Tm[4]     = {4096, 6144, 8192, 4096};
    const int rowoff[4] = {0, 4096, 10240, 18432};
    const int bid = blockIdx.x;
    const int tid = threadIdx.x;

    if (bid < 32) {
        int chain = bid*256 + tid;
        int m = chain >> 11, entry = chain & 2047;
        float* p = ws + SP_OFF + (size_t)spoff[m]*2048 + entry;
        const int n = nslots[m];
        float s = 0.0f;
        #pragma unroll 8
        for (int k = 0; k < n; ++k) {
            float v = p[(size_t)k*2048];
            s += v;
            p[(size_t)k*2048] = s;
        }
    } else if (bid < 34) {
        const float* td = ws + TD_OFF;
        int* ctab = (int*)(ws + C_OFF);
        int g = (bid - 32)*256 + tid;
        int m = g >> 7, tile = (g >> 1) & 63, bound = g & 1;
        float t = td[tile*64 + (bound ? 63 : 0)];
        const float* t2 = td + rowoff[m];
        int lo = 0, hi = Tm[m];
        while (lo < hi) {
            int mid = (lo + hi) >> 1;
            if (t2[mid] <= t) lo = mid + 1; else hi = mid;
        }
        ctab[g] = lo;
    } else {
        float4 z = make_float4(0.f, 0.f, 0.f, 0.f);
        #pragma unroll
        for (int k = 0; k < 16; ++k)
            ((float4*)out)[(bid - 34)*4096 + k*256 + tid] = z;
    }
}

__global__ __launch_bounds__(256) void k_query(
    const float* __restrict__ x0, const float* __restrict__ x1,
    const float* __restrict__ x2, const float* __restrict__ x3,
    float* __restrict__ ws, float* __restrict__ out)
{
    __shared__ unsigned short qs[64*72];
    __shared__ unsigned short kc[64*72];
    __shared__ unsigned short vt[32*72];
    __shared__ unsigned short st[32*72];
    __shared__ unsigned short ps[64*72];
    __shared__ float tq[64];
    __shared__ float tcs[64];

    const int tid  = threadIdx.x;
    const int m    = blockIdx.x & 3;
    const int tile = (blockIdx.x >> 2) & 63;
    const int slot = blockIdx.x >> 8;
    const int i0   = tile * 64;

    const float* Xs[4] = {x0, x1, x2, x3};
    const int rowoff[4] = {0, 4096, 10240, 18432};
    const int spoff[4]  = {0, 65, 162, 291};
    const float* X = Xs[m];

    const int* ctab = (const int*)(ws + C_OFF);
    const int c_lo = ctab[m*128 + tile*2 + 0];
    const int c_hi = ctab[m*128 + tile*2 + 1];
    const int B0   = c_lo >> 6;
    const int Bhi  = (c_hi + 63) >> 6;

    if (slot == 1 && B0 + 1 >= Bhi) return;

    const unsigned short* Qg = (const unsigned short*)(ws + QB_OFF);
    const unsigned short* Kg = (const unsigned short*)(ws + KB_OFF) + (size_t)rowoff[m]*64;
    const float* td = ws + TD_OFF;
    const float* sp = ws + SP_OFF + (size_t)(spoff[m] + B0)*2048;

    #pragma unroll
    for (int k = 0; k < 4; ++k) {
        int idx = k*256 + tid;
        int rr = idx >> 4, c4 = (idx & 15) * 4;
        *(ushort4*)&qs[rr*72 + c4] = *(const ushort4*)&Qg[(size_t)(i0 + rr)*64 + c4];
    }
    if (slot == 0) {
        #pragma unroll
        for (int k = 0; k < 8; ++k) {
            int idx = k*256 + tid;
            int d = idx >> 5, e = idx & 31;
            st[e*72 + d] = f2bf(sp[idx]);
        }
    }
    if (tid < 64) tq[tid] = td[i0 + tid];
    __syncthreads();

    const int w    = tid >> 6;
    const int lane = tid & 63;
    const int lm   = lane & 15;
    const int q    = lane >> 4;

    float t1v[16];
    #pragma unroll
    for (int mt = 0; mt < 4; ++mt)
        #pragma unroll
        for (int r = 0; r < 4; ++r)
            t1v[mt*4 + r] = tq[mt*16 + q*4 + r];

    short8 qa[4][2];
    #pragma unroll
    for (int mt = 0; mt < 4; ++mt) {
        qa[mt][0] = *(const short8*)&qs[(mt*16+lm)*72 + q*8];
        qa[mt][1] = *(const short8*)&qs[(mt*16+lm)*72 + 32 + q*8];
    }

    floatx4 accO[2];
    accO[0] = (floatx4){0.f, 0.f, 0.f, 0.f};
    accO[1] = (floatx4){0.f, 0.f, 0.f, 0.f};

    if (slot == 0) {
        #pragma unroll
        for (int nt = 0; nt < 2; ++nt) {
            #pragma unroll
            for (int ks = 0; ks < 2; ++ks) {
                short8 b = *(const short8*)&st[(nt*16+lm)*72 + ks*32 + q*8];
                accO[nt] = MFMA16(qa[w][ks], b, accO[nt]);
            }
        }
    }

    #pragma unroll 1
    for (int B = B0 + slot; B < Bhi; B += 2) {
        __syncthreads();
        #pragma unroll
        for (int k = 0; k < 4; ++k) {
            int idx = k*256 + tid;
            int j = idx >> 4, c4 = (idx & 15) * 4;
            *(ushort4*)&kc[j*72 + c4] = *(const ushort4*)&Kg[(size_t)(B*64 + j)*64 + c4];
        }
        #pragma unroll
        for (int k = 0; k < 2; ++k) {
            int idx = k*256 + tid;
            int j = idx >> 3, e4 = (idx & 7) * 4;
            float4 v = *(const float4*)&X[(size_t)(B*64 + j)*64 + e4];
            vt[(e4+0)*72 + j] = f2bf(v.x);
            vt[(e4+1)*72 + j] = f2bf(v.y);
            vt[(e4+2)*72 + j] = f2bf(v.z);
            vt[(e4+3)*72 + j] = f2bf(v.w);
        }
        if (tid < 64) tcs[tid] = td[rowoff[m] + B*64 + tid];
        __syncthreads();

        {
            short8 bk0 = *(const short8*)&kc[(w*16+lm)*72 + q*8];
            short8 bk1 = *(const short8*)&kc[(w*16+lm)*72 + 32 + q*8];
            float t2j = tcs[w*16 + lm];
            #pragma unroll
            for (int mt = 0; mt < 4; ++mt) {
                floatx4 f = {0.f, 0.f, 0.f, 0.f};
                f = MFMA16(qa[mt][0], bk0, f);
                f = MFMA16(qa[mt][1], bk1, f);
                #pragma unroll
                for (int r = 0; r < 4; ++r) {
                    float p = (t2j <= t1v[mt*4 + r]) ? f[r] : 0.0f;
                    ps[(mt*16 + q*4 + r)*72 + w*16 + lm] = f2bf(p);
                }
            }
        }
        __syncthreads();

        {
            short8 pa0 = *(const short8*)&ps[(w*16+lm)*72 + q*8];
            short8 pa1 = *(const short8*)&ps[(w*16+lm)*72 + 32 + q*8];
            #pragma unroll
            for (int nt = 0; nt < 2; ++nt) {
                short8 bv0 = *(const short8*)&vt[(nt*16+lm)*72 + q*8];
                short8 bv1 = *(const short8*)&vt[(nt*16+lm)*72 + 32 + q*8];
                accO[nt] = MFMA16(pa0, bv0, accO[nt]);
                accO[nt] = MFMA16(pa1, bv1, accO[nt]);
            }
        }
    }

    #pragma unroll
    for (int nt = 0; nt < 2; ++nt)
        #pragma unroll
        for (int r = 0; r < 4; ++r) {
            int i = w*16 + q*4 + r;
            int e = nt*16 + lm;
            atomicAdd(&out[(size_t)(i0 + i)*32 + e], accO[nt][r]);
        }
}

extern "C" void kernel_launch(void* const* d_in, const int* in_sizes, int n_in,
                              void* d_out, int out_size, void* d_ws, size_t ws_size,
                              hipStream_t stream) {
    const float* x0   = (const float*)d_in[0];
    const float* x1   = (const float*)d_in[1];
    const float* x2   = (const float*)d_in[2];
    const float* x3   = (const float*)d_in[3];
    const float* wq_w = (const float*)d_in[4];
    const float* wq_b = (const float*)d_in[5];
    const float* wk_w = (const float*)d_in[6];
    const float* wk_b = (const float*)d_in[7];
    float* ws  = (float*)d_ws;
    float* out = (float*)d_out;

    void* args[10] = {
        (void*)&x0, (void*)&x1, (void*)&x2, (void*)&x3,
        (void*)&wq_w, (void*)&wq_b, (void*)&wk_w, (void*)&wk_b,
        (void*)&ws, (void*)&out
    };
    hipError_t rc = hipLaunchCooperativeKernel((const void*)k_all,
                                               dim3(416), dim3(256),
                                               args, 0, stream);
    if (rc != hipSuccess) {
        (void)hipGetLastError();   // clear sticky error, fall back to 3-kernel path
        hipLaunchKernelGGL(k_fused,  dim3(416), dim3(256), 0, stream,
                           x0, x1, x2, x3, wq_w, wq_b, wk_w, wk_b, ws);
        hipLaunchKernelGGL(k_prefix, dim3(42),  dim3(256), 0, stream, ws, out);
        hipLaunchKernelGGL(k_query,  dim3(512), dim3(256), 0, stream,
                           x0, x1, x2, x3, ws, out);
    }
}

// Round 2
// 105.854 us; speedup vs baseline: 2.8916x; 2.8916x over previous
//
#include <hip/hip_runtime.h>

// Problem constants
//   m1:(1,1,4096,64) m2:(1,1,6144,64) m3:(1,1,8192,64) m4:(1,1,4096,64) fp32
//   WQ_w:(3,64,64) WQ_b:(3,64) WK_w:(4,3,64,64) WK_b:(4,3,64)
//   out:(1,4096,32) fp32
//
// Two dispatches (cooperative grid.sync measured ~75us/sync on this runtime
// in R1 -- disqualified; k_prefix eliminated instead):
//   k_fused : MLPs + bf16 Q/K stores + bf16 per-chunk K^T.V sums + t2 dense
//             + zero out.
//   k_query : per-block wave-parallel searchsorted (c_lo/c_hi) + on-the-fly
//             S-prefix column-sum (slot 0/1 each sum half the chunks) +
//             boundary-chunk masked attention + atomicAdd.
//
// Workspace layout (float units):
//   Qb   bf16 [4096][64]                 @ 0          (131072 fl)
//   Kb   bf16 per module [T_m][64]       @ 131072     (720896 fl)
//   SP   bf16 352 slots x 2048 (d*32+e)  @ 851968     (360448 fl used)
//   TD   fp32 dense t2 per module        @ 1581056    (22528 fl)

#define QB_OFF   0
#define KB_OFF   131072
#define SP_OFF   851968
#define TD_OFF   1581056

typedef __attribute__((ext_vector_type(8))) short short8;    // bf16 frag (4 VGPR)
typedef __attribute__((ext_vector_type(4))) float floatx4;   // MFMA C/D

__device__ __forceinline__ unsigned short f2bf(float f) {
    union { float f; unsigned u; } v; v.f = f;
    unsigned r = v.u + 0x7fff + ((v.u >> 16) & 1);   // RNE
    return (unsigned short)(r >> 16);
}
__device__ __forceinline__ float bf2f(unsigned short h) {
    union { unsigned u; float f; } v; v.u = ((unsigned)h) << 16;
    return v.f;
}

#define MFMA16(a,b,c) __builtin_amdgcn_mfma_f32_16x16x32_bf16((a),(b),(c),0,0,0)

// ---------------------------------------------------------------------------
// Fused: 3-layer MLP (bf16 MFMA) + bf16 Q/K store + bf16 chunk K^T.V sums +
// out zeroing. 64-row tiles -> 416 blocks, one up-front global batch per
// block (X tile + all 3 W layers), one barrier per layer.
__global__ __launch_bounds__(256) void k_fused(
    const float* __restrict__ x0, const float* __restrict__ x1,
    const float* __restrict__ x2, const float* __restrict__ x3,
    const float* __restrict__ wq_w, const float* __restrict__ wq_b,
    const float* __restrict__ wk_w, const float* __restrict__ wk_b,
    float* __restrict__ ws, float* __restrict__ out)
{
    __shared__ unsigned short H0[64*72];      // act ping [row][col]
    __shared__ unsigned short H1[64*72];      // act pong
    __shared__ unsigned short Wt[3][64*72];   // W^T all layers [c][d]
    __shared__ unsigned short KT[64*72];      // K^T [d][j]
    __shared__ unsigned short VT[32*72];      // V^T [e][j]

    const int tid = threadIdx.x;
    const int bid = blockIdx.x;

    int task, rb;
    if (bid < 64)       { task = 0; rb = bid; }
    else if (bid < 128) { task = 1; rb = bid - 64; }
    else if (bid < 224) { task = 2; rb = bid - 128; }
    else if (bid < 352) { task = 3; rb = bid - 224; }
    else                { task = 4; rb = bid - 352; }

    const float* Xs[4] = {x0, x1, x2, x3};
    const int rowoff[4] = {0, 4096, 10240, 18432};
    const int spoffc[4] = {0, 64, 160, 288};      // chunk-slot base per module

    const float* X; const float* W; const float* Bv; int mm = -1;
    if (task == 0) { X = x0; W = wq_w; Bv = wq_b; }
    else {
        mm = task - 1;
        X = Xs[mm]; W = wk_w + mm*3*64*64; Bv = wk_b + mm*3*64;
    }

    const int row0 = rb * 64;

    // ---- one up-front global batch: X tile + all 3 W layers ----
    {
        const float4* X4 = (const float4*)(X + (size_t)row0*64);
        #pragma unroll
        for (int k = 0; k < 4; ++k) {
            int idx = k*256 + tid;            // 0..1023 float4s
            float4 v = X4[idx];
            int rr = idx >> 4, c4 = (idx & 15) * 4;
            ushort4 h;
            h.x = f2bf(v.x); h.y = f2bf(v.y); h.z = f2bf(v.z); h.w = f2bf(v.w);
            *(ushort4*)&H0[rr*72 + c4] = h;
        }
        const float4* W4 = (const float4*)W;
        #pragma unroll
        for (int k = 0; k < 12; ++k) {
            int idx = k*256 + tid;            // 0..3071 float4s over 3 layers
            float4 v = W4[idx];
            int l = idx >> 10, rest = idx & 1023;
            int d = rest >> 4, c4 = (rest & 15) * 4;
            Wt[l][(c4+0)*72 + d] = f2bf(v.x);
            Wt[l][(c4+1)*72 + d] = f2bf(v.y);
            Wt[l][(c4+2)*72 + d] = f2bf(v.z);
            Wt[l][(c4+3)*72 + d] = f2bf(v.w);
        }
    }
    // task-0 blocks zero the output (k_query only atomicAdds)
    if (task == 0) {
        float4 z = make_float4(0.f, 0.f, 0.f, 0.f);
        ((float4*)out)[bid*512 + tid] = z;
        ((float4*)out)[bid*512 + 256 + tid] = z;
    }
    // dense timestamps (fp32, never through bf16)
    if (task > 0 && tid < 64)
        ws[TD_OFF + rowoff[mm] + row0 + tid] = X[(size_t)(row0 + tid)*64 + 63];
    __syncthreads();

    const int w    = tid >> 6;      // wave id = n-tile
    const int lane = tid & 63;
    const int lm   = lane & 15;
    const int q    = lane >> 4;
    const int col  = w*16 + lm;

    // ---- 3 MFMA layers, ONE barrier each (ping-pong) ----
    #pragma unroll 1
    for (int l = 0; l < 3; ++l) {
        const unsigned short* Hin  = (l & 1) ? H1 : H0;
        unsigned short*       Hout = (l & 1) ? H0 : H1;
        float bias = Bv[l*64 + col];
        short8 b0 = *(const short8*)&Wt[l][col*72 + q*8];
        short8 b1 = *(const short8*)&Wt[l][col*72 + 32 + q*8];
        #pragma unroll
        for (int mt = 0; mt < 4; ++mt) {
            floatx4 acc = {bias, bias, bias, bias};
            short8 a0 = *(const short8*)&Hin[(mt*16+lm)*72 + q*8];
            short8 a1 = *(const short8*)&Hin[(mt*16+lm)*72 + 32 + q*8];
            acc = MFMA16(a0, b0, acc);
            acc = MFMA16(a1, b1, acc);
            int r0 = mt*16 + q*4;
            #pragma unroll
            for (int r = 0; r < 4; ++r) {
                float f = acc[r];
                if (l < 2) f = fmaxf(f, 0.0f);
                unsigned short hb = f2bf(f);
                Hout[(r0+r)*72 + col] = hb;
                if (l == 2 && task > 0) KT[col*72 + r0 + r] = hb;  // K^T [d][j]
            }
        }
        __syncthreads();
    }

    // coalesced bf16 global store of final activations (in H1)
    {
        unsigned short* dst = (task == 0)
            ? (unsigned short*)(ws + QB_OFF)
            : (unsigned short*)(ws + KB_OFF) + (size_t)rowoff[mm]*64;
        #pragma unroll
        for (int k = 0; k < 4; ++k) {
            int idx = k*256 + tid;            // 0..1023 ushort4s
            int rr = idx >> 4, c4 = (idx & 15) * 4;
            *(ushort4*)&dst[(size_t)(row0 + rr)*64 + c4] = *(ushort4*)&H1[rr*72 + c4];
        }
    }
    if (task == 0) return;

    // stage V^T (X cols 0..31)
    {
        #pragma unroll
        for (int k = 0; k < 2; ++k) {
            int idx = k*256 + tid;            // 0..511 float4s
            int j = idx >> 3, e4 = (idx & 7) * 4;
            float4 v = *(const float4*)&X[(size_t)(row0 + j)*64 + e4];
            VT[(e4+0)*72 + j] = f2bf(v.x);
            VT[(e4+1)*72 + j] = f2bf(v.y);
            VT[(e4+2)*72 + j] = f2bf(v.z);
            VT[(e4+3)*72 + j] = f2bf(v.w);
        }
    }
    __syncthreads();

    // chunk sum S[d][e] = sum_j K[j][d] V[j][e]; wave w owns d-tile w.
    // Stored bf16 at slot rb (consumed bf16 downstream anyway).
    {
        unsigned short* slotH = (unsigned short*)(ws + SP_OFF)
                              + (size_t)(spoffc[mm] + rb) * 2048;
        #pragma unroll
        for (int nt = 0; nt < 2; ++nt) {
            floatx4 acc = {0.f, 0.f, 0.f, 0.f};
            #pragma unroll
            for (int ks = 0; ks < 2; ++ks) {
                short8 aa = *(const short8*)&KT[col*72 + ks*32 + q*8];
                short8 bb = *(const short8*)&VT[(nt*16+lm)*72 + ks*32 + q*8];
                acc = MFMA16(aa, bb, acc);
            }
            #pragma unroll
            for (int r = 0; r < 4; ++r)
                slotH[(w*16 + q*4 + r)*32 + nt*16 + lm] = f2bf(acc[r]);
        }
    }
}

// ---------------------------------------------------------------------------
// Tiled MFMA query kernel, chunk-slot split: 512 blocks = (module m, 64-query
// tile, slot in {0,1}). Self-contained: computes its own c-bounds via a
// wave-parallel 64-ary searchsorted, and its own S-prefix by column-summing
// its half of the bf16 chunk slots (no scan kernel, no ctab).
__global__ __launch_bounds__(256) void k_query(
    const float* __restrict__ x0, const float* __restrict__ x1,
    const float* __restrict__ x2, const float* __restrict__ x3,
    float* __restrict__ ws, float* __restrict__ out)
{
    __shared__ unsigned short qs[64*72];   // Q  [i][d]
    __shared__ unsigned short kc[64*72];   // K  [j][d]  (chunk)
    __shared__ unsigned short vt[32*72];   // V^T [e][j] (chunk)
    __shared__ unsigned short st[32*72];   // S^T [e][d] (partial prefix)
    __shared__ unsigned short ps[64*72];   // masked P [i][j] (chunk)
    __shared__ float tq[64];               // t1 tile (fp32!)
    __shared__ float tcs[64];              // t2 chunk (fp32!)
    __shared__ int   SB[2];                // c_lo, c_hi

    const int tid  = threadIdx.x;
    const int m    = blockIdx.x & 3;
    const int tile = (blockIdx.x >> 2) & 63;
    const int slot = blockIdx.x >> 8;      // 0 or 1
    const int i0   = tile * 64;

    const int w    = tid >> 6;
    const int lane = tid & 63;
    const int lm   = lane & 15;
    const int q    = lane >> 4;

    const float* Xs[4] = {x0, x1, x2, x3};
    const int rowoff[4] = {0, 4096, 10240, 18432};
    const int spoffc[4] = {0, 64, 160, 288};
    const int Tm[4]     = {4096, 6144, 8192, 4096};
    const float* X = Xs[m];

    const unsigned short* Qg  = (const unsigned short*)(ws + QB_OFF);
    const unsigned short* Kg  = (const unsigned short*)(ws + KB_OFF) + (size_t)rowoff[m]*64;
    const unsigned short* SPH = (const unsigned short*)(ws + SP_OFF);
    const float* td = ws + TD_OFF;

    // Q tile -> LDS
    #pragma unroll
    for (int k = 0; k < 4; ++k) {
        int idx = k*256 + tid;
        int rr = idx >> 4, c4 = (idx & 15) * 4;
        *(ushort4*)&qs[rr*72 + c4] = *(const ushort4*)&Qg[(size_t)(i0 + rr)*64 + c4];
    }
    if (tid < 64) tq[tid] = td[i0 + tid];

    // wave-parallel 64-ary searchsorted(t2, t, side='right'):
    // wave0 -> c_lo (t = t1[i0]), wave1 -> c_hi (t = t1[i0+63]).
    // Invariant: result in [lo, hi]; preds are prefix-true (t2 sorted).
    if (w < 2) {
        float t = td[i0 + (w ? 63 : 0)];
        const float* t2 = td + rowoff[m];
        int lo = 0, hi = Tm[m];
        while (hi - lo > 64) {
            int step = (hi - lo + 63) >> 6;
            int pos = lo + lane*step;
            bool pred = (pos < hi) && (t2[pos] <= t);
            int c = __popcll(__ballot(pred));
            int nhi = (c < 64) ? (lo + c*step) : hi;
            if (nhi > hi) nhi = hi;
            if (c) lo = lo + (c-1)*step + 1;
            hi = nhi;
        }
        int pos = lo + lane;
        bool pred = (pos < hi) && (t2[pos] <= t);
        int c = __popcll(__ballot(pred));
        if (lane == 0) SB[w] = lo + c;
    }
    __syncthreads();

    const int c_lo = SB[0];
    const int c_hi = SB[1];
    const int B0   = c_lo >> 6;
    const int Bhi  = (c_hi + 63) >> 6;

    // on-the-fly S-prefix: this block sums chunk slots {slot, slot+2, ...} < B0.
    // Thread owns 8 consecutive entries (one uint4 per slot), fp32 accumulate.
    {
        float sacc[8] = {0.f,0.f,0.f,0.f,0.f,0.f,0.f,0.f};
        const unsigned short* sp0 = SPH + (size_t)spoffc[m]*2048 + tid*8;
        #pragma unroll 2
        for (int k = slot; k < B0; k += 2) {
            uint4 pv = *(const uint4*)(sp0 + (size_t)k*2048);
            sacc[0] += bf2f((unsigned short)(pv.x & 0xffffu));
            sacc[1] += bf2f((unsigned short)(pv.x >> 16));
            sacc[2] += bf2f((unsigned short)(pv.y & 0xffffu));
            sacc[3] += bf2f((unsigned short)(pv.y >> 16));
            sacc[4] += bf2f((unsigned short)(pv.z & 0xffffu));
            sacc[5] += bf2f((unsigned short)(pv.z >> 16));
            sacc[6] += bf2f((unsigned short)(pv.w & 0xffffu));
            sacc[7] += bf2f((unsigned short)(pv.w >> 16));
        }
        int d0 = (tid*8) >> 5, e0 = (tid*8) & 31;   // 8 consecutive e, same d
        #pragma unroll
        for (int k = 0; k < 8; ++k)
            st[(e0+k)*72 + d0] = f2bf(sacc[k]);
    }
    __syncthreads();

    float t1v[16];
    #pragma unroll
    for (int mt = 0; mt < 4; ++mt)
        #pragma unroll
        for (int r = 0; r < 4; ++r)
            t1v[mt*4 + r] = tq[mt*16 + q*4 + r];

    short8 qa[4][2];
    #pragma unroll
    for (int mt = 0; mt < 4; ++mt) {
        qa[mt][0] = *(const short8*)&qs[(mt*16+lm)*72 + q*8];
        qa[mt][1] = *(const short8*)&qs[(mt*16+lm)*72 + 32 + q*8];
    }

    floatx4 accO[2];
    accO[0] = (floatx4){0.f, 0.f, 0.f, 0.f};
    accO[1] = (floatx4){0.f, 0.f, 0.f, 0.f};

    // Q . S_partial (both slots; each holds its half of the prefix)
    #pragma unroll
    for (int nt = 0; nt < 2; ++nt) {
        #pragma unroll
        for (int ks = 0; ks < 2; ++ks) {
            short8 b = *(const short8*)&st[(nt*16+lm)*72 + ks*32 + q*8];
            accO[nt] = MFMA16(qa[w][ks], b, accO[nt]);
        }
    }

    // boundary chunks: masked attention, odd/even split across slots
    #pragma unroll 1
    for (int B = B0 + slot; B < Bhi; B += 2) {
        __syncthreads();
        #pragma unroll
        for (int k = 0; k < 4; ++k) {
            int idx = k*256 + tid;
            int j = idx >> 4, c4 = (idx & 15) * 4;
            *(ushort4*)&kc[j*72 + c4] = *(const ushort4*)&Kg[(size_t)(B*64 + j)*64 + c4];
        }
        #pragma unroll
        for (int k = 0; k < 2; ++k) {
            int idx = k*256 + tid;
            int j = idx >> 3, e4 = (idx & 7) * 4;
            float4 v = *(const float4*)&X[(size_t)(B*64 + j)*64 + e4];
            vt[(e4+0)*72 + j] = f2bf(v.x);
            vt[(e4+1)*72 + j] = f2bf(v.y);
            vt[(e4+2)*72 + j] = f2bf(v.z);
            vt[(e4+3)*72 + j] = f2bf(v.w);
        }
        if (tid < 64) tcs[tid] = td[rowoff[m] + B*64 + tid];
        __syncthreads();

        {
            short8 bk0 = *(const short8*)&kc[(w*16+lm)*72 + q*8];
            short8 bk1 = *(const short8*)&kc[(w*16+lm)*72 + 32 + q*8];
            float t2j = tcs[w*16 + lm];
            #pragma unroll
            for (int mt = 0; mt < 4; ++mt) {
                floatx4 f = {0.f, 0.f, 0.f, 0.f};
                f = MFMA16(qa[mt][0], bk0, f);
                f = MFMA16(qa[mt][1], bk1, f);
                #pragma unroll
                for (int r = 0; r < 4; ++r) {
                    float p = (t2j <= t1v[mt*4 + r]) ? f[r] : 0.0f;
                    ps[(mt*16 + q*4 + r)*72 + w*16 + lm] = f2bf(p);
                }
            }
        }
        __syncthreads();

        {
            short8 pa0 = *(const short8*)&ps[(w*16+lm)*72 + q*8];
            short8 pa1 = *(const short8*)&ps[(w*16+lm)*72 + 32 + q*8];
            #pragma unroll
            for (int nt = 0; nt < 2; ++nt) {
                short8 bv0 = *(const short8*)&vt[(nt*16+lm)*72 + q*8];
                short8 bv1 = *(const short8*)&vt[(nt*16+lm)*72 + 32 + q*8];
                accO[nt] = MFMA16(pa0, bv0, accO[nt]);
                accO[nt] = MFMA16(pa1, bv1, accO[nt]);
            }
        }
    }

    #pragma unroll
    for (int nt = 0; nt < 2; ++nt)
        #pragma unroll
        for (int r = 0; r < 4; ++r) {
            int i = w*16 + q*4 + r;
            int e = nt*16 + lm;
            atomicAdd(&out[(size_t)(i0 + i)*32 + e], accO[nt][r]);
        }
}

extern "C" void kernel_launch(void* const* d_in, const int* in_sizes, int n_in,
                              void* d_out, int out_size, void* d_ws, size_t ws_size,
                              hipStream_t stream) {
    const float* x0   = (const float*)d_in[0];
    const float* x1   = (const float*)d_in[1];
    const float* x2   = (const float*)d_in[2];
    const float* x3   = (const float*)d_in[3];
    const float* wq_w = (const float*)d_in[4];
    const float* wq_b = (const float*)d_in[5];
    const float* wk_w = (const float*)d_in[6];
    const float* wk_b = (const float*)d_in[7];
    float* ws  = (float*)d_ws;
    float* out = (float*)d_out;

    hipLaunchKernelGGL(k_fused, dim3(416), dim3(256), 0, stream,
                       x0, x1, x2, x3, wq_w, wq_b, wk_w, wk_b, ws, out);
    hipLaunchKernelGGL(k_query, dim3(512), dim3(256), 0, stream,
                       x0, x1, x2, x3, ws, out);
}

// Round 3
// 98.322 us; speedup vs baseline: 3.1131x; 1.0766x over previous
//
#include <hip/hip_runtime.h>

// Problem constants
//   m1:(1,1,4096,64) m2:(1,1,6144,64) m3:(1,1,8192,64) m4:(1,1,4096,64) fp32
//   WQ_w:(3,64,64) WQ_b:(3,64) WK_w:(4,3,64,64) WK_b:(4,3,64)
//   out:(1,4096,32) fp32
//
// Two dispatches:
//   k_fused : MLPs + bf16 Q/K stores + bf16 per-chunk K^T.V sums + bf16 V^T
//             chunk store (VB) + t2 dense + zero out.
//   k_query : per-block wave-parallel searchsorted (c_lo/c_hi) + on-the-fly
//             S-prefix column-sum (slot 0/1 each sum half the chunks) +
//             boundary-chunk masked attention (K,V both bf16 from ws) +
//             atomicAdd.
//
// Workspace layout (float units):
//   Qb   bf16 [4096][64]                 @ 0          (131072 fl)
//   Kb   bf16 per module [T_m][64]       @ 131072     (720896 fl)
//   SP   bf16 352 slots x 2048 (d*32+e)  @ 851968     (360448 fl)
//   VB   bf16 352 slots x 2048 (e*64+j)  @ 1212416    (360448 fl)
//   TD   fp32 dense t2 per module        @ 1581056    (22528 fl)

#define QB_OFF   0
#define KB_OFF   131072
#define SP_OFF   851968
#define VB_OFF   1212416
#define TD_OFF   1581056

typedef __attribute__((ext_vector_type(8))) short short8;    // bf16 frag (4 VGPR)
typedef __attribute__((ext_vector_type(4))) float floatx4;   // MFMA C/D

__device__ __forceinline__ unsigned short f2bf(float f) {
    union { float f; unsigned u; } v; v.f = f;
    unsigned r = v.u + 0x7fff + ((v.u >> 16) & 1);   // RNE
    return (unsigned short)(r >> 16);
}
__device__ __forceinline__ float bf2f(unsigned short h) {
    union { unsigned u; float f; } v; v.u = ((unsigned)h) << 16;
    return v.f;
}

#define MFMA16(a,b,c) __builtin_amdgcn_mfma_f32_16x16x32_bf16((a),(b),(c),0,0,0)

// ---------------------------------------------------------------------------
// Fused: 3-layer MLP (bf16 MFMA) + bf16 Q/K store + bf16 chunk K^T.V sums +
// bf16 V^T chunk store + out zeroing. 64-row tiles -> 416 blocks. One explicit
// register batch of global loads (X tile + all 3 W layers) up front; V^T
// staged from those registers (no tail global re-read); VB store issued right
// after the first barrier so its latency hides under the MFMA layers.
__global__ __launch_bounds__(256) void k_fused(
    const float* __restrict__ x0, const float* __restrict__ x1,
    const float* __restrict__ x2, const float* __restrict__ x3,
    const float* __restrict__ wq_w, const float* __restrict__ wq_b,
    const float* __restrict__ wk_w, const float* __restrict__ wk_b,
    float* __restrict__ ws, float* __restrict__ out)
{
    __shared__ unsigned short H0[64*72];      // act ping [row][col]
    __shared__ unsigned short H1[64*72];      // act pong
    __shared__ unsigned short Wt[3][64*72];   // W^T all layers [c][d]
    __shared__ unsigned short KT[64*72];      // K^T [d][j]
    __shared__ unsigned short VT[32*72];      // V^T [e][j]

    const int tid = threadIdx.x;
    const int bid = blockIdx.x;

    int task, rb;
    if (bid < 64)       { task = 0; rb = bid; }
    else if (bid < 128) { task = 1; rb = bid - 64; }
    else if (bid < 224) { task = 2; rb = bid - 128; }
    else if (bid < 352) { task = 3; rb = bid - 224; }
    else                { task = 4; rb = bid - 352; }

    const float* Xs[4] = {x0, x1, x2, x3};
    const int rowoff[4] = {0, 4096, 10240, 18432};
    const int spoffc[4] = {0, 64, 160, 288};      // chunk-slot base per module

    const float* X; const float* W; const float* Bv; int mm = -1;
    if (task == 0) { X = x0; W = wq_w; Bv = wq_b; }
    else {
        mm = task - 1;
        X = Xs[mm]; W = wk_w + mm*3*64*64; Bv = wk_b + mm*3*64;
    }

    const int row0 = rb * 64;

    // ---- one up-front register batch: X tile + all 3 W layers ----
    {
        const float4* X4 = (const float4*)(X + (size_t)row0*64);
        float4 xv[4];
        #pragma unroll
        for (int k = 0; k < 4; ++k) xv[k] = X4[k*256 + tid];
        const float4* W4 = (const float4*)W;
        float4 wv[12];
        #pragma unroll
        for (int k = 0; k < 12; ++k) wv[k] = W4[k*256 + tid];

        // X -> H0 [row][col] bf16, and V^T [e][j] for e<32 from the same regs
        #pragma unroll
        for (int k = 0; k < 4; ++k) {
            int idx = k*256 + tid;            // 0..1023 float4s
            int rr = idx >> 4, c4 = (idx & 15) * 4;
            ushort4 h;
            h.x = f2bf(xv[k].x); h.y = f2bf(xv[k].y);
            h.z = f2bf(xv[k].z); h.w = f2bf(xv[k].w);
            *(ushort4*)&H0[rr*72 + c4] = h;
            if (task > 0 && c4 < 32) {
                VT[(c4+0)*72 + rr] = h.x;
                VT[(c4+1)*72 + rr] = h.y;
                VT[(c4+2)*72 + rr] = h.z;
                VT[(c4+3)*72 + rr] = h.w;
            }
        }
        // W -> Wt transposed [c][d]
        #pragma unroll
        for (int k = 0; k < 12; ++k) {
            int idx = k*256 + tid;            // 0..3071 float4s over 3 layers
            int l = idx >> 10, rest = idx & 1023;
            int d = rest >> 4, c4 = (rest & 15) * 4;
            Wt[l][(c4+0)*72 + d] = f2bf(wv[k].x);
            Wt[l][(c4+1)*72 + d] = f2bf(wv[k].y);
            Wt[l][(c4+2)*72 + d] = f2bf(wv[k].z);
            Wt[l][(c4+3)*72 + d] = f2bf(wv[k].w);
        }
    }
    // task-0 blocks zero the output (k_query only atomicAdds)
    if (task == 0) {
        float4 z = make_float4(0.f, 0.f, 0.f, 0.f);
        ((float4*)out)[bid*512 + tid] = z;
        ((float4*)out)[bid*512 + 256 + tid] = z;
    }
    // dense timestamps (fp32, never through bf16)
    if (task > 0 && tid < 64)
        ws[TD_OFF + rowoff[mm] + row0 + tid] = X[(size_t)(row0 + tid)*64 + 63];
    __syncthreads();

    // fire-and-forget V^T chunk store (bf16); latency hides under MFMA layers
    if (task > 0) {
        unsigned short* VBg = (unsigned short*)(ws + VB_OFF)
                            + (size_t)(spoffc[mm] + rb) * 2048;
        #pragma unroll
        for (int k = 0; k < 2; ++k) {
            int p = k*256 + tid;              // 0..511 ushort4 groups
            int e = p >> 4, j4 = (p & 15) * 4;
            *(ushort4*)&VBg[p*4] = *(ushort4*)&VT[e*72 + j4];
        }
    }

    const int w    = tid >> 6;      // wave id = n-tile
    const int lane = tid & 63;
    const int lm   = lane & 15;
    const int q    = lane >> 4;
    const int col  = w*16 + lm;

    // ---- 3 MFMA layers, ONE barrier each (ping-pong) ----
    #pragma unroll 1
    for (int l = 0; l < 3; ++l) {
        const unsigned short* Hin  = (l & 1) ? H1 : H0;
        unsigned short*       Hout = (l & 1) ? H0 : H1;
        float bias = Bv[l*64 + col];
        short8 b0 = *(const short8*)&Wt[l][col*72 + q*8];
        short8 b1 = *(const short8*)&Wt[l][col*72 + 32 + q*8];
        #pragma unroll
        for (int mt = 0; mt < 4; ++mt) {
            floatx4 acc = {bias, bias, bias, bias};
            short8 a0 = *(const short8*)&Hin[(mt*16+lm)*72 + q*8];
            short8 a1 = *(const short8*)&Hin[(mt*16+lm)*72 + 32 + q*8];
            acc = MFMA16(a0, b0, acc);
            acc = MFMA16(a1, b1, acc);
            int r0 = mt*16 + q*4;
            #pragma unroll
            for (int r = 0; r < 4; ++r) {
                float f = acc[r];
                if (l < 2) f = fmaxf(f, 0.0f);
                unsigned short hb = f2bf(f);
                Hout[(r0+r)*72 + col] = hb;
                if (l == 2 && task > 0) KT[col*72 + r0 + r] = hb;  // K^T [d][j]
            }
        }
        __syncthreads();
    }

    // coalesced bf16 global store of final activations (in H1)
    {
        unsigned short* dst = (task == 0)
            ? (unsigned short*)(ws + QB_OFF)
            : (unsigned short*)(ws + KB_OFF) + (size_t)rowoff[mm]*64;
        #pragma unroll
        for (int k = 0; k < 4; ++k) {
            int idx = k*256 + tid;            // 0..1023 ushort4s
            int rr = idx >> 4, c4 = (idx & 15) * 4;
            *(ushort4*)&dst[(size_t)(row0 + rr)*64 + c4] = *(ushort4*)&H1[rr*72 + c4];
        }
    }
    if (task == 0) return;

    // chunk sum S[d][e] = sum_j K[j][d] V[j][e]; wave w owns d-tile w.
    // KT written before the last layer barrier, VT before the first: both valid.
    {
        unsigned short* slotH = (unsigned short*)(ws + SP_OFF)
                              + (size_t)(spoffc[mm] + rb) * 2048;
        #pragma unroll
        for (int nt = 0; nt < 2; ++nt) {
            floatx4 acc = {0.f, 0.f, 0.f, 0.f};
            #pragma unroll
            for (int ks = 0; ks < 2; ++ks) {
                short8 aa = *(const short8*)&KT[col*72 + ks*32 + q*8];
                short8 bb = *(const short8*)&VT[(nt*16+lm)*72 + ks*32 + q*8];
                acc = MFMA16(aa, bb, acc);
            }
            #pragma unroll
            for (int r = 0; r < 4; ++r)
                slotH[(w*16 + q*4 + r)*32 + nt*16 + lm] = f2bf(acc[r]);
        }
    }
}

// ---------------------------------------------------------------------------
// Tiled MFMA query kernel, chunk-slot split: 512 blocks = (module m, 64-query
// tile, slot in {0,1}). Self-contained: computes its own c-bounds via a
// wave-parallel 64-ary searchsorted, and its own S-prefix by column-summing
// its half of the bf16 chunk slots (4-deep load batching). K and V both come
// from ws in bf16 (no fp32 V re-read, no transpose in the chunk loop).
__global__ __launch_bounds__(256) void k_query(
    float* __restrict__ ws, float* __restrict__ out)
{
    __shared__ unsigned short qs[64*72];   // Q  [i][d]
    __shared__ unsigned short kc[64*72];   // K  [j][d]  (chunk)
    __shared__ unsigned short vt[32*72];   // V^T [e][j] (chunk)
    __shared__ unsigned short st[32*72];   // S^T [e][d] (partial prefix)
    __shared__ unsigned short ps[64*72];   // masked P [i][j] (chunk)
    __shared__ float tq[64];               // t1 tile (fp32!)
    __shared__ float tcs[64];              // t2 chunk (fp32!)
    __shared__ int   SB[2];                // c_lo, c_hi

    const int tid  = threadIdx.x;
    const int m    = blockIdx.x & 3;
    const int tile = (blockIdx.x >> 2) & 63;
    const int slot = blockIdx.x >> 8;      // 0 or 1
    const int i0   = tile * 64;

    const int w    = tid >> 6;
    const int lane = tid & 63;
    const int lm   = lane & 15;
    const int q    = lane >> 4;

    const int rowoff[4] = {0, 4096, 10240, 18432};
    const int spoffc[4] = {0, 64, 160, 288};
    const int Tm[4]     = {4096, 6144, 8192, 4096};

    const unsigned short* Qg  = (const unsigned short*)(ws + QB_OFF);
    const unsigned short* Kg  = (const unsigned short*)(ws + KB_OFF) + (size_t)rowoff[m]*64;
    const unsigned short* SPH = (const unsigned short*)(ws + SP_OFF);
    const unsigned short* VBH = (const unsigned short*)(ws + VB_OFF);
    const float* td = ws + TD_OFF;

    // Q tile -> LDS
    #pragma unroll
    for (int k = 0; k < 4; ++k) {
        int idx = k*256 + tid;
        int rr = idx >> 4, c4 = (idx & 15) * 4;
        *(ushort4*)&qs[rr*72 + c4] = *(const ushort4*)&Qg[(size_t)(i0 + rr)*64 + c4];
    }
    if (tid < 64) tq[tid] = td[i0 + tid];

    // wave-parallel 64-ary searchsorted(t2, t, side='right'):
    // wave0 -> c_lo (t = t1[i0]), wave1 -> c_hi (t = t1[i0+63]).
    if (w < 2) {
        float t = td[i0 + (w ? 63 : 0)];
        const float* t2 = td + rowoff[m];
        int lo = 0, hi = Tm[m];
        while (hi - lo > 64) {
            int step = (hi - lo + 63) >> 6;
            int pos = lo + lane*step;
            bool pred = (pos < hi) && (t2[pos] <= t);
            int c = __popcll(__ballot(pred));
            int nhi = (c < 64) ? (lo + c*step) : hi;
            if (nhi > hi) nhi = hi;
            if (c) lo = lo + (c-1)*step + 1;
            hi = nhi;
        }
        int pos = lo + lane;
        bool pred = (pos < hi) && (t2[pos] <= t);
        int c = __popcll(__ballot(pred));
        if (lane == 0) SB[w] = lo + c;
    }
    __syncthreads();

    const int c_lo = SB[0];
    const int c_hi = SB[1];
    const int B0   = c_lo >> 6;
    const int Bhi  = (c_hi + 63) >> 6;

    // on-the-fly S-prefix: this block sums chunk slots {slot, slot+2, ...} < B0.
    // Thread owns 8 consecutive entries (one uint4 per slot); 4 loads in flight.
    {
        float sacc[8] = {0.f,0.f,0.f,0.f,0.f,0.f,0.f,0.f};
        const unsigned short* sp0 = SPH + (size_t)spoffc[m]*2048 + tid*8;
#define ACC8(pv) do { \
            sacc[0] += bf2f((unsigned short)((pv).x & 0xffffu)); \
            sacc[1] += bf2f((unsigned short)((pv).x >> 16)); \
            sacc[2] += bf2f((unsigned short)((pv).y & 0xffffu)); \
            sacc[3] += bf2f((unsigned short)((pv).y >> 16)); \
            sacc[4] += bf2f((unsigned short)((pv).z & 0xffffu)); \
            sacc[5] += bf2f((unsigned short)((pv).z >> 16)); \
            sacc[6] += bf2f((unsigned short)((pv).w & 0xffffu)); \
            sacc[7] += bf2f((unsigned short)((pv).w >> 16)); \
        } while (0)
        int k = slot;
        for (; k + 6 < B0; k += 8) {
            uint4 p0 = *(const uint4*)(sp0 + (size_t)(k  )*2048);
            uint4 p1 = *(const uint4*)(sp0 + (size_t)(k+2)*2048);
            uint4 p2 = *(const uint4*)(sp0 + (size_t)(k+4)*2048);
            uint4 p3 = *(const uint4*)(sp0 + (size_t)(k+6)*2048);
            ACC8(p0); ACC8(p1); ACC8(p2); ACC8(p3);
        }
        for (; k < B0; k += 2) {
            uint4 p0 = *(const uint4*)(sp0 + (size_t)k*2048);
            ACC8(p0);
        }
#undef ACC8
        int d0 = (tid*8) >> 5, e0 = (tid*8) & 31;   // 8 consecutive e, same d
        #pragma unroll
        for (int k2 = 0; k2 < 8; ++k2)
            st[(e0+k2)*72 + d0] = f2bf(sacc[k2]);
    }
    __syncthreads();

    float t1v[16];
    #pragma unroll
    for (int mt = 0; mt < 4; ++mt)
        #pragma unroll
        for (int r = 0; r < 4; ++r)
            t1v[mt*4 + r] = tq[mt*16 + q*4 + r];

    short8 qa[4][2];
    #pragma unroll
    for (int mt = 0; mt < 4; ++mt) {
        qa[mt][0] = *(const short8*)&qs[(mt*16+lm)*72 + q*8];
        qa[mt][1] = *(const short8*)&qs[(mt*16+lm)*72 + 32 + q*8];
    }

    floatx4 accO[2];
    accO[0] = (floatx4){0.f, 0.f, 0.f, 0.f};
    accO[1] = (floatx4){0.f, 0.f, 0.f, 0.f};

    // Q . S_partial (both slots; each holds its half of the prefix)
    #pragma unroll
    for (int nt = 0; nt < 2; ++nt) {
        #pragma unroll
        for (int ks = 0; ks < 2; ++ks) {
            short8 b = *(const short8*)&st[(nt*16+lm)*72 + ks*32 + q*8];
            accO[nt] = MFMA16(qa[w][ks], b, accO[nt]);
        }
    }

    // boundary chunks: masked attention, odd/even split across slots
    #pragma unroll 1
    for (int B = B0 + slot; B < Bhi; B += 2) {
        __syncthreads();
        #pragma unroll
        for (int k = 0; k < 4; ++k) {
            int idx = k*256 + tid;
            int j = idx >> 4, c4 = (idx & 15) * 4;
            *(ushort4*)&kc[j*72 + c4] = *(const ushort4*)&Kg[(size_t)(B*64 + j)*64 + c4];
        }
        {
            const unsigned short* VBg = VBH + (size_t)(spoffc[m] + B)*2048;
            #pragma unroll
            for (int k = 0; k < 2; ++k) {
                int p = k*256 + tid;          // 0..511 ushort4 groups
                int e = p >> 4, j4 = (p & 15) * 4;
                *(ushort4*)&vt[e*72 + j4] = *(const ushort4*)&VBg[p*4];
            }
        }
        if (tid < 64) tcs[tid] = td[rowoff[m] + B*64 + tid];
        __syncthreads();

        {
            short8 bk0 = *(const short8*)&kc[(w*16+lm)*72 + q*8];
            short8 bk1 = *(const short8*)&kc[(w*16+lm)*72 + 32 + q*8];
            float t2j = tcs[w*16 + lm];
            #pragma unroll
            for (int mt = 0; mt < 4; ++mt) {
                floatx4 f = {0.f, 0.f, 0.f, 0.f};
                f = MFMA16(qa[mt][0], bk0, f);
                f = MFMA16(qa[mt][1], bk1, f);
                #pragma unroll
                for (int r = 0; r < 4; ++r) {
                    float p = (t2j <= t1v[mt*4 + r]) ? f[r] : 0.0f;
                    ps[(mt*16 + q*4 + r)*72 + w*16 + lm] = f2bf(p);
                }
            }
        }
        __syncthreads();

        {
            short8 pa0 = *(const short8*)&ps[(w*16+lm)*72 + q*8];
            short8 pa1 = *(const short8*)&ps[(w*16+lm)*72 + 32 + q*8];
            #pragma unroll
            for (int nt = 0; nt < 2; ++nt) {
                short8 bv0 = *(const short8*)&vt[(nt*16+lm)*72 + q*8];
                short8 bv1 = *(const short8*)&vt[(nt*16+lm)*72 + 32 + q*8];
                accO[nt] = MFMA16(pa0, bv0, accO[nt]);
                accO[nt] = MFMA16(pa1, bv1, accO[nt]);
            }
        }
    }

    #pragma unroll
    for (int nt = 0; nt < 2; ++nt)
        #pragma unroll
        for (int r = 0; r < 4; ++r) {
            int i = w*16 + q*4 + r;
            int e = nt*16 + lm;
            atomicAdd(&out[(size_t)(i0 + i)*32 + e], accO[nt][r]);
        }
}

extern "C" void kernel_launch(void* const* d_in, const int* in_sizes, int n_in,
                              void* d_out, int out_size, void* d_ws, size_t ws_size,
                              hipStream_t stream) {
    const float* x0   = (const float*)d_in[0];
    const float* x1   = (const float*)d_in[1];
    const float* x2   = (const float*)d_in[2];
    const float* x3   = (const float*)d_in[3];
    const float* wq_w = (const float*)d_in[4];
    const float* wq_b = (const float*)d_in[5];
    const float* wk_w = (const float*)d_in[6];
    const float* wk_b = (const float*)d_in[7];
    float* ws  = (float*)d_ws;
    float* out = (float*)d_out;

    hipLaunchKernelGGL(k_fused, dim3(416), dim3(256), 0, stream,
                       x0, x1, x2, x3, wq_w, wq_b, wk_w, wk_b, ws, out);
    hipLaunchKernelGGL(k_query, dim3(512), dim3(256), 0, stream, ws, out);
}